// Round 9
// baseline (41.152 us; speedup 1.0000x reference)
//
#include <hip/hip_runtime.h>
#include <hip/hip_bf16.h>
#include <stdint.h>

// SVR polynomial-kernel prediction:
//   out[m] = sum_n alpha[n] * (1 + x_p[m].X[n])^4 + b
// m=16384, n=8192, d=64, all fp32 in/out.
// R9 = R8 2-phase LDS dbuf skeleton with wave-owns-n-tile split:
//   - wave w owns cols [w*16,w*16+16) of each chunk and ALL 128 m-rows
//     -> LDS reads 8->2 ds_read_b128/lane/chunk (CU LDS-read 10.3->2.6us)
//   - cross-wave row combine via 2KB LDS reduce at block end (NO atomics --
//     R7 lesson) + partials/finalize unchanged
//   - A: 8 m-tiles x 2 k-slices from xbf, register-resident (64 VGPR)
//   - X pre-swizzled in global so global_load_lds stays linear (rule 21);
//     swizzled ds_read: row rr=w*16+r, slot=(bh*4+g)^(rr&7)  (R8-proven)
//   - alpha folded: a4-prescaled Xs + a4 C-init; epilogue 2 VALU/elem

typedef __attribute__((ext_vector_type(8))) short bf16x8;
typedef __attribute__((ext_vector_type(8))) unsigned short ushort8;
typedef __attribute__((ext_vector_type(4))) float f32x4;

#define MM 16384
#define NN 8192
#define DD 64
#define NSPLIT 8           // n-splits -> partial slices
#define CHUNK 64           // n-cols per LDS chunk
#define CHUNKS_PER_BLK 16  // 8192 / (8*64)
#define BM 128             // m-rows per block
#define MT 8               // m-tiles per wave (all rows)

__device__ __forceinline__ unsigned short f2bf(float f) {
    uint32_t u = __float_as_uint(f);
    uint32_t r = (u + 0x7FFFu + ((u >> 16) & 1u)) >> 16;  // RNE
    return (unsigned short)r;
}

__device__ __forceinline__ void gll16(const void* g, void* l) {
    __builtin_amdgcn_global_load_lds(
        (const __attribute__((address_space(1))) unsigned int*)g,
        (__attribute__((address_space(3))) unsigned int*)l, 16, 0, 0);
}

// xp -> xbf linear row-major [16384][64] bf16.
// X  -> Xs swizzled: element (n,k) at shorts:
//   (n>>6)*4096 + (n&63)*64 + ((k>>3) ^ (n&7))*8 + (k&7),  prescaled by a4[n].
// alpha4f[n] = alpha[n]^(1/4).
__global__ void convert_kernel(const float* __restrict__ xp,
                               const float* __restrict__ X,
                               const float* __restrict__ alpha,
                               unsigned short* __restrict__ xbf,
                               unsigned short* __restrict__ Xs,
                               float* __restrict__ alpha4f) {
    const int xp4 = MM * DD / 4;          // 262144 float4 units
    const int xu = NN * DD / 8;           // 65536 16B units
    const int tot = xp4 + xu;
    int tid0 = blockIdx.x * blockDim.x + threadIdx.x;
    if (tid0 < NN) alpha4f[tid0] = sqrtf(sqrtf(alpha[tid0]));
    int stride = gridDim.x * blockDim.x;
    for (int i = tid0; i < tot; i += stride) {
        if (i < xp4) {
            float4 v = ((const float4*)xp)[i];
            ushort4 o;
            o.x = f2bf(v.x); o.y = f2bf(v.y); o.z = f2bf(v.z); o.w = f2bf(v.w);
            *(ushort4*)(xbf + (size_t)i * 4) = o;
        } else {
            int u = i - xp4;
            int n = u >> 3;
            int slot = u & 7;
            float a4 = sqrtf(sqrtf(alpha[n]));
            float4 va = ((const float4*)X)[n * 16 + slot * 2];
            float4 vb = ((const float4*)X)[n * 16 + slot * 2 + 1];
            ushort8 o;
            o[0] = f2bf(va.x * a4); o[1] = f2bf(va.y * a4);
            o[2] = f2bf(va.z * a4); o[3] = f2bf(va.w * a4);
            o[4] = f2bf(vb.x * a4); o[5] = f2bf(vb.y * a4);
            o[6] = f2bf(vb.z * a4); o[7] = f2bf(vb.w * a4);
            size_t dst = (size_t)(n >> 6) * 4096 + (n & 63) * 64
                       + ((slot ^ (n & 7)) * 8);
            *(ushort8*)(Xs + dst) = o;
        }
    }
}

__global__ __launch_bounds__(256) void svr_main(
        const unsigned short* __restrict__ xbf,
        const unsigned short* __restrict__ Xs,
        const float* __restrict__ alpha4f,
        float* __restrict__ partials) {
    __shared__ char smem[16384];          // 2 x 8KB chunk buffers
    const int tid  = threadIdx.x;
    const int lane = tid & 63;
    const int w    = tid >> 6;            // wave 0..3 owns cols [w*16, w*16+16)
    const int r    = lane & 15;           // A-row-in-tile / B-col-in-tile
    const int g    = lane >> 4;           // k-slice selector
    const int mgroup = blockIdx.x >> 3;   // 0..127
    const int ns     = blockIdx.x & 7;    // 0..7

    // A fragments: 8 m-tiles x 2 k-slices, register-resident
    bf16x8 a[MT][2];
#pragma unroll
    for (int mt = 0; mt < MT; ++mt)
#pragma unroll
        for (int ks = 0; ks < 2; ++ks)
            a[mt][ks] = *(const bf16x8*)(
                xbf + (size_t)(mgroup * BM + mt * 16 + r) * DD
                    + ks * 32 + g * 8);

    f32x4 red[MT];
#pragma unroll
    for (int mt = 0; mt < MT; ++mt) red[mt] = (f32x4){0.f, 0.f, 0.f, 0.f};

    const int chunk0 = ns * CHUNKS_PER_BLK;
    const int rr = w * 16 + r;            // this wave's chunk-local col/row

    // prologue: stage chunk0 into buf0; preload alpha for chunk0
    {
        const char* gs = (const char*)Xs + (size_t)chunk0 * 8192 + tid * 16;
        char* lb = smem + w * 1024;       // wave-uniform base; +lane*16 implicit
        gll16(gs, lb);
        gll16(gs + 4096, lb + 4096);
    }
    float av_cur = alpha4f[chunk0 * CHUNK + rr];
    __syncthreads();

    int cur = 0;
#pragma unroll 1
    for (int c = 0; c < CHUNKS_PER_BLK; ++c) {
        float av_nxt;
        if (c + 1 < CHUNKS_PER_BLK) {      // stage next chunk + next alpha
            const char* gs = (const char*)Xs
                           + (size_t)(chunk0 + c + 1) * 8192 + tid * 16;
            char* lb = smem + (cur ^ 1) * 8192 + w * 1024;
            gll16(gs, lb);
            gll16(gs + 4096, lb + 4096);
            av_nxt = alpha4f[(chunk0 + c + 1) * CHUNK + rr];
        }
        // B fragments for this wave's 16 cols (2 ds_read_b128 total)
        const char* rowp = smem + cur * 8192 + rr * 128;
        bf16x8 b0 = *(const bf16x8*)(rowp + ((g ^ (rr & 7)) * 16));
        bf16x8 b1 = *(const bf16x8*)(rowp + (((4 + g) ^ (rr & 7)) * 16));
        // acc C-init = a4 so acc_final = a4*(1 + x.X)
        f32x4 acc[MT];
#pragma unroll
        for (int mt = 0; mt < MT; ++mt)
            acc[mt] = (f32x4){av_cur, av_cur, av_cur, av_cur};
#pragma unroll
        for (int mt = 0; mt < MT; ++mt)
            acc[mt] = __builtin_amdgcn_mfma_f32_16x16x32_bf16(a[mt][0], b0, acc[mt], 0, 0, 0);
#pragma unroll
        for (int mt = 0; mt < MT; ++mt)
            acc[mt] = __builtin_amdgcn_mfma_f32_16x16x32_bf16(a[mt][1], b1, acc[mt], 0, 0, 0);
        // epilogue: red += t^4
#pragma unroll
        for (int mt = 0; mt < MT; ++mt)
#pragma unroll
            for (int i = 0; i < 4; ++i) {
                float t = acc[mt][i];
                float t2 = t * t;
                red[mt][i] = fmaf(t2, t2, red[mt][i]);
            }
        __syncthreads();
        cur ^= 1;
        if (c + 1 < CHUNKS_PER_BLK) av_cur = av_nxt;
    }

    // 1) shuffle-reduce across the 16 column-lanes (r) within each wave
#pragma unroll
    for (int mt = 0; mt < MT; ++mt)
#pragma unroll
        for (int i = 0; i < 4; ++i) {
            float v = red[mt][i];
            v += __shfl_xor(v, 1);
            v += __shfl_xor(v, 2);
            v += __shfl_xor(v, 4);
            v += __shfl_xor(v, 8);
            red[mt][i] = v;
        }
    // 2) cross-wave combine via LDS (all chunk reads done: final barrier
    //    of the loop already passed) -- rows live at mt*16 + g*4 + i
    float* sred = (float*)smem;           // 4 x 128 floats = 2KB
    if (r == 0) {
#pragma unroll
        for (int mt = 0; mt < MT; ++mt)
#pragma unroll
            for (int i = 0; i < 4; ++i)
                sred[w * BM + mt * 16 + g * 4 + i] = red[mt][i];
    }
    __syncthreads();
    if (tid < BM) {
        float s = sred[tid] + sred[BM + tid] + sred[2 * BM + tid]
                + sred[3 * BM + tid];
        partials[(size_t)ns * MM + mgroup * BM + tid] = s;
    }
}

__global__ void finalize_kernel(const float* __restrict__ partials,
                                const float* __restrict__ bbias,
                                float* __restrict__ out) {
    int m = blockIdx.x * blockDim.x + threadIdx.x;
    if (m < MM) {
        float s = bbias[0];
#pragma unroll
        for (int c = 0; c < NSPLIT; ++c) s += partials[(size_t)c * MM + m];
        out[m] = s;
    }
}

extern "C" void kernel_launch(void* const* d_in, const int* in_sizes, int n_in,
                              void* d_out, int out_size, void* d_ws, size_t ws_size,
                              hipStream_t stream) {
    const float* xp    = (const float*)d_in[0];
    const float* X     = (const float*)d_in[1];
    const float* alpha = (const float*)d_in[2];
    const float* b     = (const float*)d_in[3];
    float* out = (float*)d_out;

    // ws: xbf 2MB | Xs 1MB | alpha4f 32KB | partials 8*16384*4 = 512KB
    unsigned short* xbf = (unsigned short*)d_ws;
    unsigned short* Xs  = xbf + (size_t)MM * DD;
    float* alpha4f = (float*)(Xs + (size_t)NN * DD);
    float* partials = alpha4f + NN;

    hipLaunchKernelGGL(convert_kernel, dim3(1280), dim3(256), 0, stream,
                       xp, X, alpha, xbf, Xs, alpha4f);

    hipLaunchKernelGGL(svr_main, dim3(128 * NSPLIT), dim3(256), 0, stream,
                       xbf, Xs, alpha4f, partials);

    hipLaunchKernelGGL(finalize_kernel, dim3(MM / 256), dim3(256), 0, stream,
                       partials, b, out);
}

// Round 10
// 33.977 us; speedup vs baseline: 1.2112x; 1.2112x over previous
//
#include <hip/hip_runtime.h>
#include <hip/hip_bf16.h>
#include <stdint.h>

// SVR polynomial-kernel prediction:
//   out[m] = sum_n alpha[n] * (1 + x_p[m].X[n])^4 + b
// m=16384, n=8192, d=64, all fp32 in/out.
// R10 = R8 skeleton + DEFERRED EPILOGUE (acc ping-pong E/O):
//   chunk c's 16 MFMAs issue into set E while chunk c-1's epilogue VALU
//   runs on set O -> matrix and VALU pipes overlap within each wave,
//   MFMA latency fully hidden (nothing in period c reads period-c MFMA).
//   Cost: 2 acc sets (+32 regs) -> NSPLIT 8->4, grid 512 = EXACTLY
//   2 blocks/CU (R9 lesson: reg growth at 4 blocks/CU -> ragged rounds).
// Proven pieces kept verbatim: pre-swizzled Xs + linear global_load_lds
// (rule 21), swizzled ds_read slot=(bh*4+g)^(rr&7), a4-prescaled Xs with
// a4 C-init, wave-owns-32-rows split, partials+finalize (no atomics).

typedef __attribute__((ext_vector_type(8))) short bf16x8;
typedef __attribute__((ext_vector_type(8))) unsigned short ushort8;
typedef __attribute__((ext_vector_type(4))) float f32x4;

#define MM 16384
#define NN 8192
#define DD 64
#define NSPLIT 4           // n-splits -> partial slices
#define CHUNK 64           // n-cols per LDS chunk
#define CHUNKS_PER_BLK 32  // 8192 / (4*64)
#define BM 128             // m-rows per block

__device__ __forceinline__ unsigned short f2bf(float f) {
    uint32_t u = __float_as_uint(f);
    uint32_t r = (u + 0x7FFFu + ((u >> 16) & 1u)) >> 16;  // RNE
    return (unsigned short)r;
}

__device__ __forceinline__ void gll16(const void* g, void* l) {
    __builtin_amdgcn_global_load_lds(
        (const __attribute__((address_space(1))) unsigned int*)g,
        (__attribute__((address_space(3))) unsigned int*)l, 16, 0, 0);
}

// xp -> xbf linear row-major [16384][64] bf16.
// X  -> Xs swizzled: element (n,k) at shorts:
//   (n>>6)*4096 + (n&63)*64 + ((k>>3) ^ (n&7))*8 + (k&7),  prescaled by a4[n].
// alpha4f[n] = alpha[n]^(1/4).
__global__ void convert_kernel(const float* __restrict__ xp,
                               const float* __restrict__ X,
                               const float* __restrict__ alpha,
                               unsigned short* __restrict__ xbf,
                               unsigned short* __restrict__ Xs,
                               float* __restrict__ alpha4f) {
    const int xp4 = MM * DD / 4;          // 262144 float4 units
    const int xu = NN * DD / 8;           // 65536 16B units
    const int tot = xp4 + xu;
    int tid0 = blockIdx.x * blockDim.x + threadIdx.x;
    if (tid0 < NN) alpha4f[tid0] = sqrtf(sqrtf(alpha[tid0]));
    int stride = gridDim.x * blockDim.x;
    for (int i = tid0; i < tot; i += stride) {
        if (i < xp4) {
            float4 v = ((const float4*)xp)[i];
            ushort4 o;
            o.x = f2bf(v.x); o.y = f2bf(v.y); o.z = f2bf(v.z); o.w = f2bf(v.w);
            *(ushort4*)(xbf + (size_t)i * 4) = o;
        } else {
            int u = i - xp4;
            int n = u >> 3;
            int slot = u & 7;
            float a4 = sqrtf(sqrtf(alpha[n]));
            float4 va = ((const float4*)X)[n * 16 + slot * 2];
            float4 vb = ((const float4*)X)[n * 16 + slot * 2 + 1];
            ushort8 o;
            o[0] = f2bf(va.x * a4); o[1] = f2bf(va.y * a4);
            o[2] = f2bf(va.z * a4); o[3] = f2bf(va.w * a4);
            o[4] = f2bf(vb.x * a4); o[5] = f2bf(vb.y * a4);
            o[6] = f2bf(vb.z * a4); o[7] = f2bf(vb.w * a4);
            size_t dst = (size_t)(n >> 6) * 4096 + (n & 63) * 64
                       + ((slot ^ (n & 7)) * 8);
            *(ushort8*)(Xs + dst) = o;
        }
    }
}

// Load B fragments for chunk at LDS buffer `bufp` (R8-proven pattern)
#define LOAD_B(bvar, bufp)                                            \
    {                                                                 \
        _Pragma("unroll")                                             \
        for (int nt = 0; nt < 4; ++nt) {                              \
            const int rr2 = nt * 16 + r;                              \
            const char* rowp = (bufp) + rr2 * 128;                    \
            _Pragma("unroll")                                         \
            for (int bh = 0; bh < 2; ++bh) {                          \
                const int slot = (bh * 4 + g) ^ (rr2 & 7);            \
                bvar[nt][bh] = *(const bf16x8*)(rowp + slot * 16);    \
            }                                                         \
        }                                                             \
    }

#define MFMA_SET(accv, bvar, avv)                                     \
    {                                                                 \
        _Pragma("unroll")                                             \
        for (int mt = 0; mt < 2; ++mt)                                \
            _Pragma("unroll")                                         \
            for (int nt = 0; nt < 4; ++nt)                            \
                accv[mt][nt] = (f32x4){avv[nt], avv[nt], avv[nt], avv[nt]}; \
        _Pragma("unroll")                                             \
        for (int bh = 0; bh < 2; ++bh)                                \
            _Pragma("unroll")                                         \
            for (int nt = 0; nt < 4; ++nt)                            \
                _Pragma("unroll")                                     \
                for (int mt = 0; mt < 2; ++mt)                        \
                    accv[mt][nt] = __builtin_amdgcn_mfma_f32_16x16x32_bf16( \
                        a[mt][bh], bvar[nt][bh], accv[mt][nt], 0, 0, 0);    \
    }

#define EPILOGUE(accv)                                                \
    {                                                                 \
        _Pragma("unroll")                                             \
        for (int mt = 0; mt < 2; ++mt)                                \
            _Pragma("unroll")                                         \
            for (int nt = 0; nt < 4; ++nt)                            \
                _Pragma("unroll")                                     \
                for (int i = 0; i < 4; ++i) {                         \
                    float t = accv[mt][nt][i];                        \
                    float t2 = t * t;                                 \
                    red[mt][i] = fmaf(t2, t2, red[mt][i]);            \
                }                                                     \
    }

#define STAGE(cidx)                                                   \
    {                                                                 \
        const char* gs = (const char*)Xs + (size_t)(cidx) * 8192 + tid * 16; \
        char* lb = smem + (cur ^ 1) * 8192 + w * 1024;                \
        gll16(gs, lb);                                                \
        gll16(gs + 4096, lb + 4096);                                  \
    }

__global__ __launch_bounds__(256) void svr_main(
        const unsigned short* __restrict__ xbf,
        const unsigned short* __restrict__ Xs,
        const float* __restrict__ alpha4f,
        float* __restrict__ partials) {
    __shared__ char smem[16384];          // 2 x 8KB chunk buffers
    const int tid  = threadIdx.x;
    const int lane = tid & 63;
    const int w    = tid >> 6;            // wave 0..3, owns rows [w*32, w*32+32)
    const int r    = lane & 15;           // row-in-tile / col-in-tile
    const int g    = lane >> 4;           // k-slice selector
    const int mgroup = blockIdx.x >> 2;   // 0..127
    const int ns     = blockIdx.x & 3;    // 0..3

    // A fragments: 2 m-tiles x 2 k-slices, regs for whole kernel
    bf16x8 a[2][2];
#pragma unroll
    for (int mt = 0; mt < 2; ++mt)
#pragma unroll
        for (int ks = 0; ks < 2; ++ks)
            a[mt][ks] = *(const bf16x8*)(
                xbf + (size_t)(mgroup * BM + w * 32 + mt * 16 + r) * DD
                    + ks * 32 + g * 8);

    f32x4 red[2];
#pragma unroll
    for (int mt = 0; mt < 2; ++mt) red[mt] = (f32x4){0.f, 0.f, 0.f, 0.f};

    const int chunk0 = ns * CHUNKS_PER_BLK;
    int cur = 0;

    // prologue: stage chunk0 into buf0; load alpha for chunk0
    {
        const char* gs = (const char*)Xs + (size_t)chunk0 * 8192 + tid * 16;
        char* lb = smem + w * 1024;
        gll16(gs, lb);
        gll16(gs + 4096, lb + 4096);
    }
    float av_c[4], av_n[4];
#pragma unroll
    for (int nt = 0; nt < 4; ++nt)
        av_c[nt] = alpha4f[chunk0 * CHUNK + nt * 16 + r];
    __syncthreads();

    f32x4 accE[2][4], accO[2][4];

#pragma unroll 1
    for (int p = 0; p < CHUNKS_PER_BLK / 2; ++p) {
        // ---- chunk c0 = 2p: MFMA -> accE; epilogue of accO (chunk c0-1) ----
        {
            const int cnext = chunk0 + 2 * p + 1;   // always < chunk0+32
            STAGE(cnext);
#pragma unroll
            for (int nt = 0; nt < 4; ++nt)
                av_n[nt] = alpha4f[cnext * CHUNK + nt * 16 + r];
        }
        {
            bf16x8 b[4][2];
            LOAD_B(b, smem + cur * 8192);
            MFMA_SET(accE, b, av_c);
        }
        if (p) EPILOGUE(accO);
        __syncthreads();
        cur ^= 1;
#pragma unroll
        for (int nt = 0; nt < 4; ++nt) av_c[nt] = av_n[nt];

        // ---- chunk c1 = 2p+1: MFMA -> accO; epilogue of accE (chunk c0) ----
        const int c1 = 2 * p + 1;
        if (c1 + 1 < CHUNKS_PER_BLK) {
            const int cnext = chunk0 + c1 + 1;
            STAGE(cnext);
#pragma unroll
            for (int nt = 0; nt < 4; ++nt)
                av_n[nt] = alpha4f[cnext * CHUNK + nt * 16 + r];
        }
        {
            bf16x8 b[4][2];
            LOAD_B(b, smem + cur * 8192);
            MFMA_SET(accO, b, av_c);
        }
        EPILOGUE(accE);
        __syncthreads();
        cur ^= 1;
        if (c1 + 1 < CHUNKS_PER_BLK) {
#pragma unroll
            for (int nt = 0; nt < 4; ++nt) av_c[nt] = av_n[nt];
        }
    }
    // trailing epilogue: last chunk's accO
    EPILOGUE(accO);

    // reduce across the 16 column-lanes (r); rows live at g*4+i per m-tile
#pragma unroll
    for (int mt = 0; mt < 2; ++mt)
#pragma unroll
        for (int i = 0; i < 4; ++i) {
            float v = red[mt][i];
            v += __shfl_xor(v, 1);
            v += __shfl_xor(v, 2);
            v += __shfl_xor(v, 4);
            v += __shfl_xor(v, 8);
            red[mt][i] = v;
        }
    if (r == 0) {
#pragma unroll
        for (int mt = 0; mt < 2; ++mt)
#pragma unroll
            for (int i = 0; i < 4; ++i) {
                int row = mgroup * BM + w * 32 + mt * 16 + g * 4 + i;
                partials[(size_t)ns * MM + row] = red[mt][i];
            }
    }
}

__global__ void finalize_kernel(const float* __restrict__ partials,
                                const float* __restrict__ bbias,
                                float* __restrict__ out) {
    int m = blockIdx.x * blockDim.x + threadIdx.x;
    if (m < MM) {
        float s = bbias[0];
#pragma unroll
        for (int c = 0; c < NSPLIT; ++c) s += partials[(size_t)c * MM + m];
        out[m] = s;
    }
}

extern "C" void kernel_launch(void* const* d_in, const int* in_sizes, int n_in,
                              void* d_out, int out_size, void* d_ws, size_t ws_size,
                              hipStream_t stream) {
    const float* xp    = (const float*)d_in[0];
    const float* X     = (const float*)d_in[1];
    const float* alpha = (const float*)d_in[2];
    const float* b     = (const float*)d_in[3];
    float* out = (float*)d_out;

    // ws: xbf 2MB | Xs 1MB | alpha4f 32KB | partials 4*16384*4 = 256KB
    unsigned short* xbf = (unsigned short*)d_ws;
    unsigned short* Xs  = xbf + (size_t)MM * DD;
    float* alpha4f = (float*)(Xs + (size_t)NN * DD);
    float* partials = alpha4f + NN;

    hipLaunchKernelGGL(convert_kernel, dim3(1280), dim3(256), 0, stream,
                       xp, X, alpha, xbf, Xs, alpha4f);

    hipLaunchKernelGGL(svr_main, dim3(128 * NSPLIT), dim3(256), 0, stream,
                       xbf, Xs, alpha4f, partials);

    hipLaunchKernelGGL(finalize_kernel, dim3(MM / 256), dim3(256), 0, stream,
                       partials, b, out);
}